// Round 4
// baseline (220.863 us; speedup 1.0000x reference)
//
#include <hip/hip_runtime.h>

// GHM-C loss, single pass + tiny reduce.
// loss = sum_b S_b / (count_b * n_nonempty) over nonempty bins b.
//
// R1 lesson: same-address device atomics = 1.2 ms cross-XCD bouncing -> per-block partials.
// R2 lesson: 10-way register binning = ~50 VALU instr/elem -> cut via LDS private hist.
// R3 lesson: wall is LATENCY, not VALU/HBM: VGPR_Count=32 left zero prefetch distance
//   (load->vmcnt(0)->compute serialization, ~50us floor). Fix: explicit double-buffered
//   register prefetch (64B/thread in flight) + __launch_bounds__(256,4) for VGPR headroom.

#define NBINS  10
#define GRID1  2048
#define BLOCK1 256

__global__ __launch_bounds__(BLOCK1, 4) void ghmc_pass1(
    const float4* __restrict__ pred4,
    const int4*   __restrict__ targ4,
    float* __restrict__ partial_s,   // [NBINS][GRID1] bin-major
    int*   __restrict__ partial_c,   // [NBINS][GRID1] bin-major
    int nvec4)
{
    // Per-thread private float histogram, bin-major: addr(b,tid)=b*256+tid
    // -> bank = tid%32 for every b -> exactly 2 lanes/bank (free, m136).
    __shared__ float hist[NBINS * BLOCK1];
    __shared__ float sred[BLOCK1 / 64][NBINS];
    __shared__ int   cred[BLOCK1 / 64][NBINS];

#pragma unroll
    for (int b = 0; b < NBINS; ++b) hist[b * BLOCK1 + threadIdx.x] = 0.0f;
    // no barrier: each thread only touches its own slots

    unsigned long long cnt = 0;   // 10 x 6-bit packed counts; <=44 elems/thread < 63

    const int tid    = threadIdx.x;
    const int i0     = blockIdx.x * BLOCK1 + tid;
    const int stride = GRID1 * BLOCK1;

    auto elem = [&](float x, int t) {
        float tf = (float)t;
        float z  = __builtin_amdgcn_rcpf(1.0f + __expf(-x));   // sigmoid
        float g  = fabsf(z - tf);
        int   bi = (int)(g * 10.0f);
        bi = bi > (NBINS - 1) ? (NBINS - 1) : bi;
        float bce = __logf(1.0f + __expf(z)) - tf * z;         // softplus(z) - t*z
        hist[bi * BLOCK1 + tid] += bce;                        // ds_read + add + ds_write
        cnt += 1ull << (6 * bi);
    };
    auto elem4 = [&](const float4& p, const int4& t) {
        elem(p.x, t.x); elem(p.y, t.y); elem(p.z, t.z); elem(p.w, t.w);
    };

    // Uniform trip count (exactly nvec4/stride full strides for every thread),
    // software-pipelined 2 float4-pairs per stage with double-buffered registers.
    const int trips = nvec4 / stride;      // = 10 for N=20.97M

    float4 P[2][2];
    int4   T[2][2];
    int cur = 0;

    if (trips > 0) {
        P[0][0] = pred4[i0];
        T[0][0] = targ4[i0];
        if (trips > 1) { P[0][1] = pred4[i0 + stride]; T[0][1] = targ4[i0 + stride]; }
    }

    for (int s = 0; s < trips; s += 2) {
        const int nxt = cur ^ 1;
        // issue next stage's loads BEFORE consuming current stage
        if (s + 2 < trips) {
            const int ip = i0 + (s + 2) * stride;
            P[nxt][0] = pred4[ip];
            T[nxt][0] = targ4[ip];
            if (s + 3 < trips) { P[nxt][1] = pred4[ip + stride]; T[nxt][1] = targ4[ip + stride]; }
        }
        elem4(P[cur][0], T[cur][0]);
        if (s + 1 < trips) elem4(P[cur][1], T[cur][1]);
        cur = nxt;
    }

    // generic tail (threads whose i0 + trips*stride still lands in range)
    const int itail = i0 + trips * stride;
    if (itail < nvec4) {
        float4 p = pred4[itail];
        int4   t = targ4[itail];
        elem4(p, t);
    }

    // read back own LDS slots; unpack packed counts
    float s[NBINS];
    int   c[NBINS];
#pragma unroll
    for (int b = 0; b < NBINS; ++b) {
        s[b] = hist[b * BLOCK1 + tid];
        c[b] = (int)((cnt >> (6 * b)) & 63ull);
    }

    // wave(64) tree reduction
#pragma unroll
    for (int b = 0; b < NBINS; ++b) {
#pragma unroll
        for (int off = 32; off > 0; off >>= 1) {
            s[b] += __shfl_down(s[b], off, 64);
            c[b] += __shfl_down(c[b], off, 64);
        }
    }

    const int wave = tid >> 6;
    if ((tid & 63) == 0) {
#pragma unroll
        for (int b = 0; b < NBINS; ++b) { sred[wave][b] = s[b]; cred[wave][b] = c[b]; }
    }
    __syncthreads();
    if (tid < NBINS) {
        int b = tid;
        partial_s[b * GRID1 + blockIdx.x] = sred[0][b] + sred[1][b] + sred[2][b] + sred[3][b];
        partial_c[b * GRID1 + blockIdx.x] = cred[0][b] + cred[1][b] + cred[2][b] + cred[3][b];
    }
}

__global__ __launch_bounds__(256) void ghmc_pass2(
    const float* __restrict__ partial_s,   // [NBINS][GRID1]
    const int*   __restrict__ partial_c,
    float* __restrict__ out,
    int nblocks)
{
    double as[NBINS];
    int    ac[NBINS];
#pragma unroll
    for (int b = 0; b < NBINS; ++b) { as[b] = 0.0; ac[b] = 0; }

    for (int j = threadIdx.x; j < nblocks; j += 256) {
#pragma unroll
        for (int b = 0; b < NBINS; ++b) {
            as[b] += (double)partial_s[b * nblocks + j];   // coalesced per bin
            ac[b] += partial_c[b * nblocks + j];
        }
    }

#pragma unroll
    for (int b = 0; b < NBINS; ++b) {
#pragma unroll
        for (int off = 32; off > 0; off >>= 1) {
            as[b] += __shfl_down(as[b], off, 64);
            ac[b] += __shfl_down(ac[b], off, 64);
        }
    }

    __shared__ double sds[4][NBINS];
    __shared__ int    sdc[4][NBINS];
    int wave = threadIdx.x >> 6;
    if ((threadIdx.x & 63) == 0) {
#pragma unroll
        for (int b = 0; b < NBINS; ++b) { sds[wave][b] = as[b]; sdc[wave][b] = ac[b]; }
    }
    __syncthreads();

    if (threadIdx.x == 0) {
        int nn = 0;
        double acc = 0.0;
#pragma unroll
        for (int b = 0; b < NBINS; ++b) {
            double sb = sds[0][b] + sds[1][b] + sds[2][b] + sds[3][b];
            int    cb = sdc[0][b] + sdc[1][b] + sdc[2][b] + sdc[3][b];
            if (cb > 0) { nn += 1; acc += sb / (double)cb; }
        }
        out[0] = (float)(acc / (double)(nn > 0 ? nn : 1));
    }
}

extern "C" void kernel_launch(void* const* d_in, const int* in_sizes, int n_in,
                              void* d_out, int out_size, void* d_ws, size_t ws_size,
                              hipStream_t stream)
{
    const float* pred = (const float*)d_in[0];
    const int*   targ = (const int*)d_in[1];
    float*       out  = (float*)d_out;

    const int n     = in_sizes[0];   // 20,971,520 (divisible by 4)
    const int nvec4 = n / 4;

    float* partial_s = (float*)d_ws;                                  // NBINS*GRID1 floats
    int*   partial_c = (int*)((char*)d_ws + GRID1 * NBINS * sizeof(float));

    ghmc_pass1<<<GRID1, BLOCK1, 0, stream>>>(
        (const float4*)pred, (const int4*)targ, partial_s, partial_c, nvec4);

    ghmc_pass2<<<1, 256, 0, stream>>>(partial_s, partial_c, out, GRID1);
}

// Round 5
// 194.115 us; speedup vs baseline: 1.1378x; 1.1378x over previous
//
#include <hip/hip_runtime.h>

// GHM-C loss, single pass + tiny reduce.
// loss = sum_b S_b / (count_b * n_nonempty) over nonempty bins b.
//
// R1 lesson: same-address device atomics = 1.2 ms cross-XCD bouncing -> per-block partials.
// R2 lesson: 10-way register binning = ~50 VALU instr/elem -> LDS private hist instead.
// R3 lesson: latency-bound (VGPR=32, zero prefetch distance) -> need SW pipeline.
// R4 lesson: runtime-indexed buffers (P[cur]) demoted to SCRATCH (VGPR 24, WRITE_SIZE
//   165 MB of spill traffic). Pipeline must be compile-time: template TRIPS, fully
//   unrolled, statically-indexed half-buffers -> stays in registers.

#define NBINS  10
#define GRID1  2048
#define BLOCK1 256

__device__ __forceinline__ void ghmc_elem(float x, int t, float* hist, int tid,
                                          unsigned long long& cnt)
{
    float tf = (float)t;
    float z  = __builtin_amdgcn_rcpf(1.0f + __expf(-x));   // sigmoid
    float g  = fabsf(z - tf);
    int   bi = (int)(g * 10.0f);
    bi = bi > (NBINS - 1) ? (NBINS - 1) : bi;
    float bce = __logf(1.0f + __expf(z)) - tf * z;         // softplus(z) - t*z
    hist[bi * BLOCK1 + tid] += bce;                        // ds_read + add + ds_write
    cnt += 1ull << (6 * bi);                               // 10x6-bit packed counts
}

__device__ __forceinline__ void ghmc_epilogue(float* hist, unsigned long long cnt,
                                              float* partial_s, int* partial_c,
                                              float (*sred)[NBINS], int (*cred)[NBINS])
{
    const int tid = threadIdx.x;
    float s[NBINS];
    int   c[NBINS];
#pragma unroll
    for (int b = 0; b < NBINS; ++b) {
        s[b] = hist[b * BLOCK1 + tid];
        c[b] = (int)((cnt >> (6 * b)) & 63ull);
    }
#pragma unroll
    for (int b = 0; b < NBINS; ++b) {
#pragma unroll
        for (int off = 32; off > 0; off >>= 1) {
            s[b] += __shfl_down(s[b], off, 64);
            c[b] += __shfl_down(c[b], off, 64);
        }
    }
    const int wave = tid >> 6;
    if ((tid & 63) == 0) {
#pragma unroll
        for (int b = 0; b < NBINS; ++b) { sred[wave][b] = s[b]; cred[wave][b] = c[b]; }
    }
    __syncthreads();
    if (tid < NBINS) {
        int b = tid;
        partial_s[b * GRID1 + blockIdx.x] = sred[0][b] + sred[1][b] + sred[2][b] + sred[3][b];
        partial_c[b * GRID1 + blockIdx.x] = cred[0][b] + cred[1][b] + cred[2][b] + cred[3][b];
    }
}

// Specialized: compile-time trip count, fully unrolled, static register buffers.
template<int TRIPS>
__global__ __launch_bounds__(BLOCK1, 4) void ghmc_pass1_t(
    const float4* __restrict__ pred4,
    const int4*   __restrict__ targ4,
    float* __restrict__ partial_s,   // [NBINS][GRID1] bin-major
    int*   __restrict__ partial_c)
{
    constexpr int HALF = TRIPS / 2;
    __shared__ float hist[NBINS * BLOCK1];
    __shared__ float sred[BLOCK1 / 64][NBINS];
    __shared__ int   cred[BLOCK1 / 64][NBINS];

    const int tid = threadIdx.x;
#pragma unroll
    for (int b = 0; b < NBINS; ++b) hist[b * BLOCK1 + tid] = 0.0f;
    // no barrier: each thread only touches its own slots

    unsigned long long cnt = 0;
    const int i0     = blockIdx.x * BLOCK1 + tid;
    const int stride = GRID1 * BLOCK1;

    // Static half-buffers: all indices compile-time -> registers, never scratch.
    float4 PA[HALF], PB[HALF];
    int4   TA[HALF], TB[HALF];

    // prologue: issue half A's loads
#pragma unroll
    for (int j = 0; j < HALF; ++j) {
        PA[j] = pred4[i0 + j * stride];
        TA[j] = targ4[i0 + j * stride];
    }
    // issue half B's loads BEFORE consuming half A (prefetch distance = 5 pairs)
#pragma unroll
    for (int j = 0; j < HALF; ++j) {
        PB[j] = pred4[i0 + (HALF + j) * stride];
        TB[j] = targ4[i0 + (HALF + j) * stride];
    }
#pragma unroll
    for (int j = 0; j < HALF; ++j) {
        ghmc_elem(PA[j].x, TA[j].x, hist, tid, cnt);
        ghmc_elem(PA[j].y, TA[j].y, hist, tid, cnt);
        ghmc_elem(PA[j].z, TA[j].z, hist, tid, cnt);
        ghmc_elem(PA[j].w, TA[j].w, hist, tid, cnt);
    }
#pragma unroll
    for (int j = 0; j < HALF; ++j) {
        ghmc_elem(PB[j].x, TB[j].x, hist, tid, cnt);
        ghmc_elem(PB[j].y, TB[j].y, hist, tid, cnt);
        ghmc_elem(PB[j].z, TB[j].z, hist, tid, cnt);
        ghmc_elem(PB[j].w, TB[j].w, hist, tid, cnt);
    }

    ghmc_epilogue(hist, cnt, partial_s, partial_c, sred, cred);
}

// Generic fallback for any size (R2-style simple grid-stride loop).
__global__ __launch_bounds__(BLOCK1) void ghmc_pass1_gen(
    const float4* __restrict__ pred4,
    const int4*   __restrict__ targ4,
    float* __restrict__ partial_s,
    int*   __restrict__ partial_c,
    int nvec4)
{
    __shared__ float hist[NBINS * BLOCK1];
    __shared__ float sred[BLOCK1 / 64][NBINS];
    __shared__ int   cred[BLOCK1 / 64][NBINS];

    const int tid = threadIdx.x;
#pragma unroll
    for (int b = 0; b < NBINS; ++b) hist[b * BLOCK1 + tid] = 0.0f;

    unsigned long long cnt = 0;
    const int i0     = blockIdx.x * BLOCK1 + tid;
    const int stride = GRID1 * BLOCK1;

    for (int i = i0; i < nvec4; i += stride) {
        float4 p = pred4[i];
        int4   t = targ4[i];
        ghmc_elem(p.x, t.x, hist, tid, cnt);
        ghmc_elem(p.y, t.y, hist, tid, cnt);
        ghmc_elem(p.z, t.z, hist, tid, cnt);
        ghmc_elem(p.w, t.w, hist, tid, cnt);
    }

    ghmc_epilogue(hist, cnt, partial_s, partial_c, sred, cred);
}

__global__ __launch_bounds__(256) void ghmc_pass2(
    const float* __restrict__ partial_s,   // [NBINS][GRID1]
    const int*   __restrict__ partial_c,
    float* __restrict__ out,
    int nblocks)
{
    double as[NBINS];
    int    ac[NBINS];
#pragma unroll
    for (int b = 0; b < NBINS; ++b) { as[b] = 0.0; ac[b] = 0; }

    for (int j = threadIdx.x; j < nblocks; j += 256) {
#pragma unroll
        for (int b = 0; b < NBINS; ++b) {
            as[b] += (double)partial_s[b * nblocks + j];   // coalesced per bin
            ac[b] += partial_c[b * nblocks + j];
        }
    }

#pragma unroll
    for (int b = 0; b < NBINS; ++b) {
#pragma unroll
        for (int off = 32; off > 0; off >>= 1) {
            as[b] += __shfl_down(as[b], off, 64);
            ac[b] += __shfl_down(ac[b], off, 64);
        }
    }

    __shared__ double sds[4][NBINS];
    __shared__ int    sdc[4][NBINS];
    int wave = threadIdx.x >> 6;
    if ((threadIdx.x & 63) == 0) {
#pragma unroll
        for (int b = 0; b < NBINS; ++b) { sds[wave][b] = as[b]; sdc[wave][b] = ac[b]; }
    }
    __syncthreads();

    if (threadIdx.x == 0) {
        int nn = 0;
        double acc = 0.0;
#pragma unroll
        for (int b = 0; b < NBINS; ++b) {
            double sb = sds[0][b] + sds[1][b] + sds[2][b] + sds[3][b];
            int    cb = sdc[0][b] + sdc[1][b] + sdc[2][b] + sdc[3][b];
            if (cb > 0) { nn += 1; acc += sb / (double)cb; }
        }
        out[0] = (float)(acc / (double)(nn > 0 ? nn : 1));
    }
}

extern "C" void kernel_launch(void* const* d_in, const int* in_sizes, int n_in,
                              void* d_out, int out_size, void* d_ws, size_t ws_size,
                              hipStream_t stream)
{
    const float* pred = (const float*)d_in[0];
    const int*   targ = (const int*)d_in[1];
    float*       out  = (float*)d_out;

    const int n     = in_sizes[0];   // 20,971,520
    const int nvec4 = n / 4;         // 5,242,880 = 10 * (2048*256) exactly

    float* partial_s = (float*)d_ws;                                  // NBINS*GRID1 floats
    int*   partial_c = (int*)((char*)d_ws + GRID1 * NBINS * sizeof(float));

    const int stride = GRID1 * BLOCK1;
    if (nvec4 == 10 * stride) {
        ghmc_pass1_t<10><<<GRID1, BLOCK1, 0, stream>>>(
            (const float4*)pred, (const int4*)targ, partial_s, partial_c);
    } else {
        ghmc_pass1_gen<<<GRID1, BLOCK1, 0, stream>>>(
            (const float4*)pred, (const int4*)targ, partial_s, partial_c, nvec4);
    }

    ghmc_pass2<<<1, 256, 0, stream>>>(partial_s, partial_c, out, GRID1);
}